// Round 1
// baseline (12955.933 us; speedup 1.0000x reference)
//
#include <hip/hip_runtime.h>
#include <cstdint>
#include <cstddef>

#define B_      16
#define N_      2048
#define NOTE_   512
#define BEAT_H_ 128
#define MEAS_H_ 64
#define NBEATS_ 256
#define NMEAS_  64
#define OUT_    11
#define D_      10
// fin = 715 (512 note + 128 beat + 64 meas + 11 prev_out)
// tin = 203 (128 beat + 64 meas + 1 tempo + 10 beat_results)

__device__ __forceinline__ float sigm_(float x) { return 1.0f / (1.0f + expf(-x)); }

// ---------------------------------------------------------------------------
// pad flags: pad[b,i] = (sum_k note_emb[b,i,k] == 0)
// one wave per row, 4 rows per 256-thread block
// ---------------------------------------------------------------------------
__global__ __launch_bounds__(256) void pad_k(const float* __restrict__ note,
                                             int* __restrict__ padf) {
    int wave = threadIdx.x >> 6, lane = threadIdx.x & 63;
    int r = blockIdx.x * 4 + wave;
    const float* row = note + ((size_t)r << 9);
    float s = 0.f;
#pragma unroll
    for (int u = 0; u < 8; ++u) s += row[lane + (u << 6)];
#pragma unroll
    for (int off = 32; off; off >>= 1) s += __shfl_xor(s, off, 64);
    if (lane == 0) padf[r] = (s == 0.0f) ? 1 : 0;
}

// ---------------------------------------------------------------------------
// tempo_pre[b,q,j] = Wih_t[j,0:128]·beat_emb[b,q] + Wih_t[j,128:192]·meas_emb[b,cm(q)]
//                    + bih_t[j] + bhh_t[j]
// grid (16 b, 16 q-tiles), 256 threads; q-tile of 16 amortizes weight reads
// ---------------------------------------------------------------------------
__global__ __launch_bounds__(256) void tempo_pre_k(
    const float* __restrict__ beat, const float* __restrict__ meas,
    const int* __restrict__ bnum, const int* __restrict__ mnum,
    const float* __restrict__ Wih_t, const float* __restrict__ bih_t,
    const float* __restrict__ bhh_t, float* __restrict__ tpre) {
    __shared__ float sin_[16][192];
    int b = blockIdx.x, qt = blockIdx.y;
    int t = threadIdx.x;
    int bn0 = bnum[b << 11], mn0 = mnum[b << 11];
    for (int idx = t; idx < 16 * 192; idx += 256) {
        int qq = idx / 192, kk = idx - qq * 192;
        int q = qt * 16 + qq;
        float v;
        if (kk < 128) {
            v = beat[(size_t)(b * NBEATS_ + q) * 128 + kk];
        } else {
            int cm = ((q + bn0) >> 2) - mn0;       // measure index for beat value q
            if (cm > 63) cm = 63;                   // q's beyond actual range are never read
            if (cm < 0) cm = 0;
            v = meas[(size_t)(b * NMEAS_ + cm) * 64 + (kk - 128)];
        }
        sin_[qq][kk] = v;
    }
    __syncthreads();
    for (int half = 0; half < 2; ++half) {
        int j = t + half * 256;
        const float* wr = Wih_t + (size_t)j * 203;
        float bias = bih_t[j] + bhh_t[j];
        float acc[16] = {};
        for (int k = 0; k < 192; ++k) {
            float w = wr[k];
#pragma unroll
            for (int qq = 0; qq < 16; ++qq) acc[qq] += w * sin_[qq][k];
        }
        for (int qq = 0; qq < 16; ++qq)
            tpre[(size_t)(b * NBEATS_ + qt * 16 + qq) * 512 + j] = acc[qq] + bias;
    }
}

// ---------------------------------------------------------------------------
// fin_pre[r, j] = [note(512) | beat(128) | meas(64)] · Wih_f[j, 0:704] + bih_f[j]+bhh_f[j]
// r = b*2048 + i; gathered-A fp32 GEMM, M=32768 N=512 K=704
// 64x64 tile, 256 threads, 4x4 microtile, K-step 16
// ---------------------------------------------------------------------------
__global__ __launch_bounds__(256) void fin_pre_gemm(
    const float* __restrict__ note, const float* __restrict__ beat,
    const float* __restrict__ meas, const int* __restrict__ bnum,
    const int* __restrict__ mnum, const float* __restrict__ Wih_f,
    const float* __restrict__ bih_f, const float* __restrict__ bhh_f,
    float* __restrict__ finp) {
    __shared__ float As[16][64];
    __shared__ float Bs[16][64];
    int t = threadIdx.x;
    int r0 = blockIdx.x * 64;
    int j0 = blockIdx.y * 64;

    // A gather setup (fixed row per thread across K loop)
    int am = t >> 2, alane = t & 3;
    int r = r0 + am;
    int b = r >> 11;
    int rb = b << 11;
    int cb = bnum[r] - bnum[rb];
    int cm = mnum[r] - mnum[rb];
    const float* arow_note = note + ((size_t)r << 9);
    const float* arow_beat = beat + ((size_t)(b * NBEATS_ + cb) << 7);
    const float* arow_meas = meas + ((size_t)(b * NMEAS_ + cm) << 6);

    int jj = t >> 2, blane = t & 3;
    const float* brow = Wih_f + (size_t)(j0 + jj) * 715;

    int tm0 = (t & 15) * 4, tn0 = (t >> 4) * 4;
    float acc[4][4] = {};

    for (int k0 = 0; k0 < 704; k0 += 16) {
        int ka = k0 + alane * 4;
        float4 av;
        if (ka < 512)      av = *(const float4*)(arow_note + ka);
        else if (ka < 640) av = *(const float4*)(arow_beat + (ka - 512));
        else               av = *(const float4*)(arow_meas + (ka - 640));
        int kb = k0 + blane * 4;
        float b0 = brow[kb], b1 = brow[kb + 1], b2 = brow[kb + 2], b3 = brow[kb + 3];
        __syncthreads();
        As[alane * 4 + 0][am] = av.x;
        As[alane * 4 + 1][am] = av.y;
        As[alane * 4 + 2][am] = av.z;
        As[alane * 4 + 3][am] = av.w;
        Bs[blane * 4 + 0][jj] = b0;
        Bs[blane * 4 + 1][jj] = b1;
        Bs[blane * 4 + 2][jj] = b2;
        Bs[blane * 4 + 3][jj] = b3;
        __syncthreads();
#pragma unroll
        for (int kk = 0; kk < 16; ++kk) {
            float4 a4 = *(const float4*)&As[kk][tm0];
            float4 b4 = *(const float4*)&Bs[kk][tn0];
            float aa[4] = {a4.x, a4.y, a4.z, a4.w};
            float bb[4] = {b4.x, b4.y, b4.z, b4.w};
#pragma unroll
            for (int mi = 0; mi < 4; ++mi)
#pragma unroll
                for (int ni = 0; ni < 4; ++ni) acc[mi][ni] += aa[mi] * bb[ni];
        }
    }
    float bias[4];
#pragma unroll
    for (int ni = 0; ni < 4; ++ni) {
        int j = j0 + tn0 + ni;
        bias[ni] = bih_f[j] + bhh_f[j];
    }
#pragma unroll
    for (int mi = 0; mi < 4; ++mi) {
        int rr = r0 + tm0 + mi;
        float4 o;
        o.x = acc[mi][0] + bias[0];
        o.y = acc[mi][1] + bias[1];
        o.z = acc[mi][2] + bias[2];
        o.w = acc[mi][3] + bias[3];
        *(float4*)(finp + ((size_t)rr << 9) + j0 + tn0) = o;
    }
}

// ---------------------------------------------------------------------------
// sequential decoder: one 512-thread block per batch element
// ---------------------------------------------------------------------------
__global__ __launch_bounds__(512, 2) void decode_seq(
    const float* __restrict__ finp, const float* __restrict__ tpre,
    const int* __restrict__ bnum, const int* __restrict__ padf,
    const float* __restrict__ Whh_f, const float* __restrict__ Wih_f,
    const float* __restrict__ Whh_t, const float* __restrict__ Wih_t,
    const float* __restrict__ W_fc, const float* __restrict__ b_fc,
    const float* __restrict__ W_tfc, const float* __restrict__ b_tfc,
    const float* __restrict__ Wa, const float* __restrict__ ba,
    const float* __restrict__ ctx, float* __restrict__ out) {
    __shared__ float hf_s[128], cf_s[128], ht_s[128], ct_s[128];
    __shared__ float g_s[512];
    __shared__ float prev_s[OUT_];     // [0] = tempo scalar, [1..10] = out
    __shared__ float cur_res[D_];      // beat_results[b, cb] (last changed-step attention)
    __shared__ float v_s[D_];
    __shared__ float c0_s;
    __shared__ float bfc_s[D_];
    __shared__ float btfc_s;
    __shared__ float red_s[2][D_];
    __shared__ float redt_s[2];
    __shared__ int bn_s[N_];
    __shared__ float xh[512][D_];      // circular history of out channels 1..10

    int tid = threadIdx.x, lane = tid & 63, wave = tid >> 6;
    int b = blockIdx.x;

    // per-thread register-resident weights
    float4 whhf[32];
    {
        const float4* wfp = (const float4*)(Whh_f + (size_t)tid * 128);
#pragma unroll
        for (int q = 0; q < 32; ++q) whhf[q] = wfp[q];
    }
    float wihf_t[OUT_];
#pragma unroll
    for (int u = 0; u < OUT_; ++u) wihf_t[u] = Wih_f[(size_t)tid * 715 + 704 + u];
    float wiht_t[OUT_];
#pragma unroll
    for (int u = 0; u < OUT_; ++u) wiht_t[u] = Wih_t[(size_t)tid * 203 + 192 + u];
    int kt = tid & 127;
    float wfc_r[D_];
#pragma unroll
    for (int d = 0; d < D_; ++d) wfc_r[d] = W_fc[d * 128 + kt];
    float wtfc_r = W_tfc[kt];

    if (tid < 128) { hf_s[tid] = 0.f; cf_s[tid] = 0.f; ht_s[tid] = 0.f; ct_s[tid] = 0.f; }
    if (tid < OUT_) prev_s[tid] = 0.f;
    if (tid < D_) {
        cur_res[tid] = 0.f;
        bfc_s[tid] = b_fc[tid];
        float vv = 0.f;
        for (int m = 0; m < D_; ++m) vv += ctx[m] * Wa[m * D_ + tid];
        v_s[tid] = vv;
    }
    if (tid == 10) {
        float cc = 0.f;
        for (int m = 0; m < D_; ++m) cc += ba[m] * ctx[m];
        c0_s = cc;
        btfc_s = b_tfc[0];
    }
    for (int k = tid; k < N_; k += 512) bn_s[k] = bnum[(b << 11) + k];
    __syncthreads();

    const float* finrow = finp + ((size_t)b << 11) * 512;
    int run_start = 0;

    for (int i = 0; i < N_; ++i) {
        int bni = bn_s[i];
        bool changed = (i == 0) || (bni != bn_s[i - 1]);
        int S_prev = run_start;          // start of run containing i-1
        if (changed) run_start = i;

        // ---- final-LSTM: precomputed input row + recurrent matvec (indep of this step) ----
        float gf = finrow[(size_t)i * 512 + tid];
        float acc2 = 0.f;
        {
            const float4* h4 = (const float4*)hf_s;
#pragma unroll
            for (int q = 0; q < 32; ++q) {
                float4 hv = h4[q];
                float4 wv = whhf[q];
                acc2 += wv.x * hv.x + wv.y * hv.y + wv.z * hv.z + wv.w * hv.w;
            }
        }

        if (changed) {
            // ---- attention over previous beat's notes [S_prev, i) (wave 0) ----
            if (wave == 0) {
                int L = i - S_prev;
                float lmax = -1e30f;
                for (int tt = lane; tt < L; tt += 64) {
                    const float* xr = xh[(S_prev + tt) & 511];
                    float s = c0_s;
#pragma unroll
                    for (int d = 0; d < D_; ++d) s += xr[d] * v_s[d];
                    lmax = fmaxf(lmax, s);
                }
#pragma unroll
                for (int off = 32; off; off >>= 1)
                    lmax = fmaxf(lmax, __shfl_xor(lmax, off, 64));
                float lsum = 0.f, lacc[D_] = {};
                for (int tt = lane; tt < L; tt += 64) {
                    const float* xr = xh[(S_prev + tt) & 511];
                    float s = c0_s;
#pragma unroll
                    for (int d = 0; d < D_; ++d) s += xr[d] * v_s[d];
                    float w = expf(s - lmax);
                    lsum += w;
#pragma unroll
                    for (int d = 0; d < D_; ++d) lacc[d] += w * xr[d];
                }
#pragma unroll
                for (int off = 32; off; off >>= 1) {
                    lsum += __shfl_xor(lsum, off, 64);
#pragma unroll
                    for (int d = 0; d < D_; ++d) lacc[d] += __shfl_xor(lacc[d], off, 64);
                }
                if (lane == 0) {
                    if (L > 0) {
                        float inv = 1.0f / lsum;
                        for (int d = 0; d < D_; ++d) cur_res[d] = lacc[d] * inv;
                    } else {
                        for (int d = 0; d < D_; ++d) cur_res[d] = 0.f;
                    }
                }
            }
            __syncthreads();
            // ---- tempo LSTM gates ----
            int cb = bni - bn_s[0];
            float gt = tpre[(size_t)(b * NBEATS_ + cb) * 512 + tid];
            gt += wiht_t[0] * prev_s[0];
#pragma unroll
            for (int d = 0; d < D_; ++d) gt += wiht_t[1 + d] * cur_res[d];
            {
                const float4* wtp = (const float4*)(Whh_t + (size_t)tid * 128);
                const float4* ht4 = (const float4*)ht_s;
#pragma unroll
                for (int q = 0; q < 32; ++q) {
                    float4 wv = wtp[q];
                    float4 hv = ht4[q];
                    gt += wv.x * hv.x + wv.y * hv.y + wv.z * hv.z + wv.w * hv.w;
                }
            }
            g_s[tid] = gt;
            __syncthreads();
            if (tid < 128) {
                float gi = g_s[tid], gff = g_s[128 + tid], gg = g_s[256 + tid],
                      go = g_s[384 + tid];
                float c2 = sigm_(gff) * ct_s[tid] + sigm_(gi) * tanhf(gg);
                float h2 = sigm_(go) * tanhf(c2);
                ct_s[tid] = c2;
                ht_s[tid] = h2;
                float p = h2 * wtfc_r;
#pragma unroll
                for (int off = 32; off; off >>= 1) p += __shfl_xor(p, off, 64);
                if (lane == 0) redt_s[wave] = p;
            }
            __syncthreads();
            if (tid == 0) prev_s[0] = redt_s[0] + redt_s[1] + btfc_s;
            __syncthreads();
        }

        // ---- final-LSTM gate finish + cell update ----
        gf += acc2;
#pragma unroll
        for (int u = 0; u < OUT_; ++u) gf += wihf_t[u] * prev_s[u];
        g_s[tid] = gf;
        __syncthreads();
        if (tid < 128) {
            float gi = g_s[tid], gff = g_s[128 + tid], gg = g_s[256 + tid],
                  go = g_s[384 + tid];
            float c2 = sigm_(gff) * cf_s[tid] + sigm_(gi) * tanhf(gg);
            float h2 = sigm_(go) * tanhf(c2);
            cf_s[tid] = c2;
            hf_s[tid] = h2;
            float po[D_];
#pragma unroll
            for (int d = 0; d < D_; ++d) po[d] = h2 * wfc_r[d];
#pragma unroll
            for (int off = 32; off; off >>= 1) {
#pragma unroll
                for (int d = 0; d < D_; ++d) po[d] += __shfl_xor(po[d], off, 64);
            }
            if (lane == 0) {
#pragma unroll
                for (int d = 0; d < D_; ++d) red_s[wave][d] = po[d];
            }
        }
        __syncthreads();
        int pd = padf[(b << 11) + i];
        if (tid < D_) {
            float od = red_s[0][tid] + red_s[1][tid] + bfc_s[tid];
            prev_s[1 + tid] = od;
            xh[i & 511][tid] = od;
            out[(size_t)((b << 11) + i) * OUT_ + 1 + tid] = pd ? 0.f : od;
        }
        if (tid == 10) out[(size_t)((b << 11) + i) * OUT_] = pd ? 0.f : prev_s[0];
        __syncthreads();
    }
}

// ---------------------------------------------------------------------------
extern "C" void kernel_launch(void* const* d_in, const int* in_sizes, int n_in,
                              void* d_out, int out_size, void* d_ws, size_t ws_size,
                              hipStream_t stream) {
    const float* note  = (const float*)d_in[0];
    const float* beat  = (const float*)d_in[1];
    const float* meas  = (const float*)d_in[2];
    const int*   bnum  = (const int*)d_in[3];
    const int*   mnum  = (const int*)d_in[4];
    const float* Wa    = (const float*)d_in[5];
    const float* ba    = (const float*)d_in[6];
    const float* ctx   = (const float*)d_in[7];
    const float* Wih_t = (const float*)d_in[8];
    const float* Whh_t = (const float*)d_in[9];
    const float* bih_t = (const float*)d_in[10];
    const float* bhh_t = (const float*)d_in[11];
    const float* Wih_f = (const float*)d_in[12];
    const float* Whh_f = (const float*)d_in[13];
    const float* bih_f = (const float*)d_in[14];
    const float* bhh_f = (const float*)d_in[15];
    const float* W_fc  = (const float*)d_in[16];
    const float* b_fc  = (const float*)d_in[17];
    const float* W_tfc = (const float*)d_in[18];
    const float* b_tfc = (const float*)d_in[19];
    float* out = (float*)d_out;

    char* ws = (char*)d_ws;
    float* finp = (float*)ws;                                   // 32768*512*4 = 64 MB
    float* tpre = (float*)(ws + (size_t)64 * 1024 * 1024);      // 16*256*512*4 = 8 MB
    int*   padf = (int*)(ws + (size_t)72 * 1024 * 1024);        // 32768*4 = 128 KB

    pad_k<<<8192, 256, 0, stream>>>(note, padf);
    tempo_pre_k<<<dim3(16, 16), 256, 0, stream>>>(beat, meas, bnum, mnum, Wih_t,
                                                  bih_t, bhh_t, tpre);
    fin_pre_gemm<<<dim3(512, 8), 256, 0, stream>>>(note, beat, meas, bnum, mnum,
                                                   Wih_f, bih_f, bhh_f, finp);
    decode_seq<<<16, 512, 0, stream>>>(finp, tpre, bnum, padf, Whh_f, Wih_f, Whh_t,
                                       Wih_t, W_fc, b_fc, W_tfc, b_tfc, Wa, ba, ctx,
                                       out);
}